// Round 10
// baseline (85.173 us; speedup 1.0000x reference)
//
#include <hip/hip_runtime.h>

// PillarLayer: fused copy + per-pillar xyz center-of-mass + BEV canvas scatter.
//
// R10 = R5 (best, 76.7us) + NON-TEMPORAL canvas scatter stores.
// Traffic model (calibrated vs harness fill kernels at ~7 TB/s):
//   minimal streams = 361 MB -> 52us; R5 measured 77us.
//   Gap == scatter RMW amplification: 3x4B stores per pillar hit ~160K
//   canvas lines from ~4.4 distinct (non-coherent) XCD L2s each
//   -> ~180 MB hidden fetch+writeback. NT stores bypass L2 allocation
//   (write-through, byte-enabled), eliminating the line round-trips.
//
// Inputs: d_in[0] pillars f32 (P,32,4); d_in[1] coors int32 (P,4) [b,x,y,z];
//         d_in[2] npoints int32 (P); d_in[3] bs; d_in[4] x_l; d_in[5] y_l.
// Output (concat f32): pillars copy | coors as f32 | npoints as f32 |
//         canvas (bs,3,y_l,x_l) with canvas[b][c][y][x] = center_c or 0.

typedef float vfloat4 __attribute__((ext_vector_type(4)));

__global__ __launch_bounds__(256) void canvas_zero(float4* __restrict__ dst, long n4) {
    long i = (long)blockIdx.x * blockDim.x + threadIdx.x;
    const long stride = (long)gridDim.x * blockDim.x;
    const float4 z = make_float4(0.f, 0.f, 0.f, 0.f);
    for (; i < n4; i += stride) dst[i] = z;
}

__global__ __launch_bounds__(256) void pillar_fused(
    const vfloat4* __restrict__ pillars4,  // P*32 (one float4 per point)
    const int4* __restrict__ coors4,       // P [b,x,y,z]
    const int* __restrict__ npoints,       // P
    const int* __restrict__ xlp,           // scalar x_l
    const int* __restrict__ ylp,           // scalar y_l
    vfloat4* __restrict__ out_pillars4,    // P*32
    float4* __restrict__ out_coors4,       // P
    float* __restrict__ out_np,            // P
    float* __restrict__ canvas,            // bs*3*y_l*x_l
    int P)
{
    const int group = blockIdx.x * (blockDim.x >> 5) + (threadIdx.x >> 5);
    const int lane  = threadIdx.x & 31;    // point index within pillar
    if (group >= P) return;
    const int p = group;

    // Coalesced: 32 lanes x 16B = 512B/pillar; wave64 = 1KB contiguous per
    // instruction. NT keeps the 327 MB stream out of L2/L3.
    const vfloat4 v = __builtin_nontemporal_load(&pillars4[(long)p * 32 + lane]);
    __builtin_nontemporal_store(v, &out_pillars4[(long)p * 32 + lane]);

    // Shuffle butterfly over the 32-lane group (xor<32 stays in-group on wave64).
    float sx = v.x, sy = v.y, sz = v.z;
    #pragma unroll
    for (int m = 16; m >= 1; m >>= 1) {
        sx += __shfl_xor(sx, m);
        sy += __shfl_xor(sy, m);
        sz += __shfl_xor(sz, m);
    }

    if (lane < 3) {
        // Same-address loads across lanes 0-2 coalesce to one request.
        const int4 c   = coors4[p];
        const int npts = npoints[p];
        const float s  = (lane == 0) ? sx : (lane == 1) ? sy : sz;
        const float val = s / (float)npts;

        const int x_l = *xlp;
        const int y_l = *ylp;
        const long cs   = (long)y_l * (long)x_l;           // plane stride
        const long base = (long)c.x * 3l * cs + (long)c.z * (long)x_l + (long)c.y;
        // NT scatter: no L2 line allocation -> no cross-XCD fetch/writeback
        // amplification on the sparse 4B stores.
        __builtin_nontemporal_store(val, &canvas[base + (long)lane * cs]);

        if (lane == 0) {
            out_coors4[p] = make_float4((float)c.x, (float)c.y, (float)c.z, (float)c.w);
            out_np[p] = (float)npts;
        }
    }
}

extern "C" void kernel_launch(void* const* d_in, const int* in_sizes, int n_in,
                              void* d_out, int out_size, void* d_ws, size_t ws_size,
                              hipStream_t stream) {
    const vfloat4* pillars4 = (const vfloat4*)d_in[0];
    const int4* coors4      = (const int4*)d_in[1];
    const int* npoints      = (const int*)d_in[2];
    const int* xlp = (const int*)d_in[4];
    const int* ylp = (const int*)d_in[5];

    const int n_pillars = in_sizes[0];   // P*128
    const int n_coors   = in_sizes[1];   // P*4
    const int P         = in_sizes[2];   // pillar count

    float* out            = (float*)d_out;
    vfloat4* out_pillars4 = (vfloat4*)out;
    float* out_coors      = out + n_pillars;
    float* out_np         = out_coors + n_coors;
    float* canvas         = out_np + P;
    const long canvas_elems = (long)out_size - n_pillars - n_coors - P;  // bs*3*y_l*x_l

    // K1: zero canvas.
    const long n4 = canvas_elems >> 2;   // canvas start is 16B-aligned here
    int zblocks = (int)((n4 + 511) / 512);
    if (zblocks > 2048) zblocks = 2048;
    canvas_zero<<<zblocks, 256, 0, stream>>>((float4*)canvas, n4);

    // K2: fused copy + reduce + scatter. 8 pillars per 256-thread block.
    const int groups_per_block = 256 / 32;
    const int blocks = (P + groups_per_block - 1) / groups_per_block;
    pillar_fused<<<blocks, 256, 0, stream>>>(
        pillars4, coors4, npoints, xlp, ylp,
        out_pillars4, (float4*)out_coors, out_np, canvas, P);
}

// Round 11
// 72.141 us; speedup vs baseline: 1.1807x; 1.1807x over previous
//
#include <hip/hip_runtime.h>

// PillarLayer: fused copy + per-pillar xyz center-of-mass + BEV canvas scatter.
//
// R11 = R5 (zero + direct scatter + NT streaming, 76.7us) with the reduction
// restructured to cut DS-pipe traffic 7.5x:
//   - 16 lanes per pillar, 2 float4 per lane (float4 idx r and r+16).
//     Each load instr = 4 x 256B segments (full lines; R6's regression was
//     16 x 64B segments). Wave covers 4 pillars = 2KB.
//   - local pair-add, then 4-step butterfly (xor 1,2,4,8) x3 = 12 ds_swizzle
//     per 2KB vs R5's 45 per 1KB.
//   - tail: r<3 lanes scatter canvas (12 active lanes, 1 instr); r==0 lanes
//     write out_coors4 (4 consecutive p -> 64B contiguous) and out_np.
//
// Inputs: d_in[0] pillars f32 (P,32,4); d_in[1] coors int32 (P,4) [b,x,y,z];
//         d_in[2] npoints int32 (P); d_in[3] bs; d_in[4] x_l; d_in[5] y_l.
// Output (concat f32): pillars copy | coors as f32 | npoints as f32 |
//         canvas (bs,3,y_l,x_l) with canvas[b][c][y][x] = center_c or 0.

typedef float vfloat4 __attribute__((ext_vector_type(4)));

__global__ __launch_bounds__(256) void canvas_zero(float4* __restrict__ dst, long n4) {
    long i = (long)blockIdx.x * blockDim.x + threadIdx.x;
    const long stride = (long)gridDim.x * blockDim.x;
    const float4 z = make_float4(0.f, 0.f, 0.f, 0.f);
    for (; i < n4; i += stride) dst[i] = z;   // cacheable: L3-resident for scatter
}

__global__ __launch_bounds__(256) void pillar_fused(
    const vfloat4* __restrict__ pillars4,  // P*32 (one float4 per point)
    const int4* __restrict__ coors4,       // P [b,x,y,z]
    const int* __restrict__ npoints,       // P
    const int* __restrict__ xlp,           // scalar x_l
    const int* __restrict__ ylp,           // scalar y_l
    vfloat4* __restrict__ out_pillars4,    // P*32
    float4* __restrict__ out_coors4,       // P
    float* __restrict__ out_np,            // P
    float* __restrict__ canvas,            // bs*3*y_l*x_l
    int P)
{
    const int tid  = threadIdx.x;
    const int g    = tid >> 4;                 // pillar group within block (0..15)
    const int r    = tid & 15;                 // lane within pillar
    const int p    = blockIdx.x * 16 + g;      // pillar id (16 pillars/block)
    if (p >= P) return;

    const long b0 = (long)p * 32;              // pillar's first float4

    // Two independent NT loads per lane; per instruction a wave covers
    // 4 x 256B full-line segments. NT keeps the 327MB stream out of L2/L3
    // so the zeroed canvas stays cache-resident for the scatter below.
    const vfloat4 v0 = __builtin_nontemporal_load(&pillars4[b0 + r]);
    const vfloat4 v1 = __builtin_nontemporal_load(&pillars4[b0 + r + 16]);
    __builtin_nontemporal_store(v0, &out_pillars4[b0 + r]);
    __builtin_nontemporal_store(v1, &out_pillars4[b0 + r + 16]);

    // Local pair-add then 4-step butterfly within the 16-lane group
    // (xor masks < 16 stay inside the group on wave64): 12 DS ops/wave/2KB.
    float sx = v0.x + v1.x, sy = v0.y + v1.y, sz = v0.z + v1.z;
    #pragma unroll
    for (int m = 8; m >= 1; m >>= 1) {
        sx += __shfl_xor(sx, m);
        sy += __shfl_xor(sy, m);
        sz += __shfl_xor(sz, m);
    }

    if (r < 3) {
        // 12 active lanes/wave; coors4[p]: 4 distinct 16B addrs (broadcast per group).
        const int4 c   = coors4[p];
        const int npts = npoints[p];
        const float s  = (r == 0) ? sx : (r == 1) ? sy : sz;
        const float val = s / (float)npts;

        const int x_l = *xlp;
        const int y_l = *ylp;
        const long cs   = (long)y_l * (long)x_l;           // plane stride
        const long base = (long)c.x * 3l * cs + (long)c.z * (long)x_l + (long)c.y;
        canvas[base + (long)r * cs] = val;                 // plane r via lane r

        if (r == 0) {
            // 4 lanes (g=0..3): out_coors4[p] consecutive -> 64B contiguous;
            // out_np[p] consecutive -> 16B contiguous.
            out_coors4[p] = make_float4((float)c.x, (float)c.y, (float)c.z, (float)c.w);
            out_np[p]     = (float)npts;
        }
    }
}

extern "C" void kernel_launch(void* const* d_in, const int* in_sizes, int n_in,
                              void* d_out, int out_size, void* d_ws, size_t ws_size,
                              hipStream_t stream) {
    const vfloat4* pillars4 = (const vfloat4*)d_in[0];
    const int4* coors4      = (const int4*)d_in[1];
    const int* npoints      = (const int*)d_in[2];
    const int* xlp = (const int*)d_in[4];
    const int* ylp = (const int*)d_in[5];

    const int n_pillars = in_sizes[0];   // P*128
    const int n_coors   = in_sizes[1];   // P*4
    const int P         = in_sizes[2];   // pillar count

    float* out            = (float*)d_out;
    vfloat4* out_pillars4 = (vfloat4*)out;
    float* out_coors      = out + n_pillars;
    float* out_np         = out_coors + n_coors;
    float* canvas         = out_np + P;
    const long canvas_elems = (long)out_size - n_pillars - n_coors - P;  // bs*3*y_l*x_l

    // K1: zero canvas (cacheable -> L3 resident for the scatter RMW).
    const long n4 = canvas_elems >> 2;   // canvas start is 16B-aligned here
    int zblocks = (int)((n4 + 511) / 512);
    if (zblocks > 2048) zblocks = 2048;
    canvas_zero<<<zblocks, 256, 0, stream>>>((float4*)canvas, n4);

    // K2: fused copy + reduce + scatter. 16 pillars per 256-thread block.
    const int blocks = (P + 15) / 16;
    pillar_fused<<<blocks, 256, 0, stream>>>(
        pillars4, coors4, npoints, xlp, ylp,
        out_pillars4, (float4*)out_coors, out_np, canvas, P);
}